// Round 1
// baseline (5431.742 us; speedup 1.0000x reference)
//
#include <hip/hip_runtime.h>
#include <hip/hip_bf16.h>

typedef _Float16 half8 __attribute__((ext_vector_type(8)));
typedef _Float16 half4 __attribute__((ext_vector_type(4)));
typedef float floatx4 __attribute__((ext_vector_type(4)));

__device__ __forceinline__ float bfu2f(unsigned short u) {
  return __uint_as_float(((unsigned)u) << 16);
}

__device__ __forceinline__ void gld16(const void* g, void* l) {
  __builtin_amdgcn_global_load_lds((const __attribute__((address_space(1))) void*)g,
                                   (__attribute__((address_space(3))) void*)l, 16, 0, 0);
}

// ---------- probe: detect fp32 vs bf16 inputs (writes flag: 1 = fp32) ----------
__global__ void probe_kernel(const unsigned short* __restrict__ w0, int* __restrict__ flag) {
  __shared__ int s;
  if (threadIdx.x == 0) s = 0;
  __syncthreads();
  int big = 0;
  for (int i = threadIdx.x; i < 2048; i += 256) {
    unsigned e = (w0[i] >> 7) & 0xFFu;
    if (e >= 134u) big = 1;  // |val| >= 128 impossible for bf16 N(0,0.7) weights
  }
  if (big) atomicOr(&s, 1);
  __syncthreads();
  if (threadIdx.x == 0) *flag = s;
}

// ---------- generic convert to fp16 ----------
__global__ void cvt_kernel(const void* __restrict__ in, _Float16* __restrict__ out, int n,
                           const int* __restrict__ flag) {
  int i = blockIdx.x * 256 + threadIdx.x;
  if (i >= n) return;
  float v = (*flag) ? ((const float*)in)[i] : bfu2f(((const unsigned short*)in)[i]);
  out[i] = (_Float16)v;
}

// ---------- transpose+convert: out[z][n][k] = in[z][k][n] (n<Nin else 0), K=1024 ----------
__global__ void tr_kernel(const void* __restrict__ in, _Float16* __restrict__ out, int Nin,
                          long inStride, long outStride, const int* __restrict__ flag) {
  __shared__ float tile[32][33];
  const int f = *flag;
  int k0 = blockIdx.x * 32, n0 = blockIdx.y * 32;
  long ib = (long)blockIdx.z * inStride;
  long ob = (long)blockIdx.z * outStride;
  int tx = threadIdx.x, ty = threadIdx.y;  // 32 x 8
#pragma unroll
  for (int i = 0; i < 4; i++) {
    int k = k0 + ty + i * 8, n = n0 + tx;
    float v = 0.f;
    if (n < Nin) {
      long idx = ib + (long)k * Nin + n;
      v = f ? ((const float*)in)[idx] : bfu2f(((const unsigned short*)in)[idx]);
    }
    tile[ty + i * 8][tx] = v;
  }
  __syncthreads();
#pragma unroll
  for (int i = 0; i < 4; i++) {
    int n = n0 + ty + i * 8, k = k0 + tx;
    out[ob + (long)n * 1024 + k] = (_Float16)tile[tx][ty + i * 8];
  }
}

// ---------- layer 0: primal + 4 tangent init ----------
__global__ __launch_bounds__(256)
void layer0_kernel(const _Float16* __restrict__ x16, const _Float16* __restrict__ W0c,
                   const __hip_bfloat16* __restrict__ b0, _Float16* __restrict__ H,
                   int chunkBase, int S1) {
  const int lb = blockIdx.x;
  const int t = threadIdx.x;
  const long gb = (long)chunkBase + lb;
  float z0 = (float)x16[gb * 4 + 0];
  float z1 = (float)x16[gb * 4 + 1];
  float z2 = (float)x16[gb * 4 + 2];
  float z3 = (float)x16[gb * 4 + 3];
  const int j0 = t * 4;
  float w[4][4];
#pragma unroll
  for (int i = 0; i < 4; i++) {
    half4 wv = *(const half4*)&W0c[i * 1024 + j0];
#pragma unroll
    for (int jj = 0; jj < 4; jj++) w[i][jj] = (float)wv[jj];
  }
  half4 o[5];
#pragma unroll
  for (int jj = 0; jj < 4; jj++) {
    float pre = z0 * w[0][jj] + z1 * w[1][jj] + z2 * w[2][jj] + z3 * w[3][jj] +
                __bfloat162float(b0[j0 + jj]);
    float s = 1.f / (1.f + __expf(-pre));
    o[0][jj] = (_Float16)(pre * s);
    float ds = s * (1.f + pre * (1.f - s));
    o[1][jj] = (_Float16)(ds * w[0][jj]);
    o[2][jj] = (_Float16)(ds * w[1][jj]);
    o[3][jj] = (_Float16)(ds * w[2][jj]);
    o[4][jj] = (_Float16)(ds * w[3][jj]);
  }
  long rowbase = (long)lb * 1024 + j0;
#pragma unroll
  for (int s = 0; s < 5; s++) *(half4*)&H[(long)s * S1 + rowbase] = o[s];
}

// ---------- fp16 GEMM: C(M x Nreal, ldc) = A(M x 1024) * Bt(N x 1024)^T + bias ----------
__global__ __launch_bounds__(256)
void gemm_f16(const _Float16* __restrict__ A, const _Float16* __restrict__ Bt,
              const __hip_bfloat16* __restrict__ bias, _Float16* __restrict__ C,
              int Nreal, int ldc) {
  constexpr int K = 1024;
  __shared__ _Float16 As[128 * 32];
  __shared__ _Float16 Bs[128 * 32];
  const int tid = threadIdx.x;
  const int wave = tid >> 6;
  const int lane = tid & 63;
  const long m0 = (long)blockIdx.x * 128;
  const int n0 = blockIdx.y * 128;

  const int srow0 = (wave * 2 + 0) * 16 + (lane >> 2);
  const int srow1 = (wave * 2 + 1) * 16 + (lane >> 2);
  const int scol = (lane & 3) * 8;
  const _Float16* gA0 = A + (m0 + srow0) * K + scol;
  const _Float16* gA1 = A + (m0 + srow1) * K + scol;
  const _Float16* gB0 = Bt + (long)(n0 + srow0) * K + scol;
  const _Float16* gB1 = Bt + (long)(n0 + srow1) * K + scol;
  _Float16* lA0 = As + (wave * 2 + 0) * 512;  // wave-uniform LDS bases
  _Float16* lA1 = As + (wave * 2 + 1) * 512;
  _Float16* lB0 = Bs + (wave * 2 + 0) * 512;
  _Float16* lB1 = Bs + (wave * 2 + 1) * 512;

  const int wm = (wave & 1) * 64;
  const int wn = (wave >> 1) * 64;
  const int fr = lane & 15;
  const int fc = (lane >> 4) * 8;

  floatx4 acc[4][4];
#pragma unroll
  for (int i = 0; i < 4; i++)
#pragma unroll
    for (int j = 0; j < 4; j++) acc[i][j] = (floatx4)(0.f);

  for (int kk = 0; kk < K; kk += 32) {
    __syncthreads();
    gld16(gA0 + kk, lA0);
    gld16(gA1 + kk, lA1);
    gld16(gB0 + kk, lB0);
    gld16(gB1 + kk, lB1);
    __syncthreads();
    half8 af[4], bf[4];
#pragma unroll
    for (int i = 0; i < 4; i++) af[i] = *(const half8*)&As[(wm + i * 16 + fr) * 32 + fc];
#pragma unroll
    for (int i = 0; i < 4; i++) bf[i] = *(const half8*)&Bs[(wn + i * 16 + fr) * 32 + fc];
#pragma unroll
    for (int mi = 0; mi < 4; mi++)
#pragma unroll
      for (int ni = 0; ni < 4; ni++)
        acc[mi][ni] = __builtin_amdgcn_mfma_f32_16x16x32_f16(af[mi], bf[ni], acc[mi][ni], 0, 0, 0);
  }

  const int col0 = lane & 15;
  const int rq = (lane >> 4) * 4;
  float bv[4];
#pragma unroll
  for (int ni = 0; ni < 4; ni++) {
    int col = n0 + wn + ni * 16 + col0;
    bv[ni] = (col < Nreal) ? __bfloat162float(bias[col]) : 0.f;
  }
#pragma unroll
  for (int mi = 0; mi < 4; mi++) {
#pragma unroll
    for (int ni = 0; ni < 4; ni++) {
      int col = n0 + wn + ni * 16 + col0;
      if (col < Nreal) {
#pragma unroll
        for (int r = 0; r < 4; r++) {
          long row = m0 + wm + mi * 16 + rq + r;
          C[row * (long)ldc + col] = (_Float16)(acc[mi][ni][r] + bv[ni]);
        }
      }
    }
  }
}

// ---------- activation: H[0]=silu(PRE[0]); H[s]=silu'(PRE[0])*PRE[s] ----------
__global__ __launch_bounds__(256)
void act_kernel(const _Float16* __restrict__ PRE, _Float16* __restrict__ H, int S1, int total) {
  int idx = blockIdx.x * 256 + threadIdx.x;
  if (idx >= total) return;
  long base = (long)idx * 8;
  half8 p0 = *(const half8*)&PRE[base];
  half8 h0;
  float ds[8];
#pragma unroll
  for (int e = 0; e < 8; e++) {
    float xv = (float)p0[e];
    float s = 1.f / (1.f + __expf(-xv));
    h0[e] = (_Float16)(xv * s);
    ds[e] = s * (1.f + xv * (1.f - s));
  }
  *(half8*)&H[base] = h0;
#pragma unroll
  for (int st = 1; st <= 4; st++) {
    half8 pt = *(const half8*)&PRE[(long)st * S1 + base];
    half8 ht;
#pragma unroll
    for (int e = 0; e < 8; e++) ht[e] = (_Float16)(ds[e] * (float)pt[e]);
    *(half8*)&H[(long)st * S1 + base] = ht;
  }
}

// ---------- finalize: softmax mixture + antisymmetric divergence; 1 wave = 1 sample ----------
__global__ __launch_bounds__(256)
void finalize_kernel(const _Float16* __restrict__ O5, void* __restrict__ outp,
                     int chunkBase, int Bc, const int* __restrict__ flag) {
  const int wid = threadIdx.x >> 6;
  const int lane = threadIdx.x & 63;  // lane == mixture index (N_MIX == 64)
  const int lb = blockIdx.x * 4 + wid;
  const long SO = (long)Bc * 448;
  const long base0 = (long)lb * 448;

  union UU { unsigned u; _Float16 h[2]; };

  float lg = (float)O5[base0 + lane];
  float vals[6];
  {
    const unsigned* vp = (const unsigned*)(O5 + base0 + 64 + lane * 6);
#pragma unroll
    for (int q = 0; q < 3; q++) {
      UU c; c.u = vp[q];
      vals[2 * q] = (float)c.h[0];
      vals[2 * q + 1] = (float)c.h[1];
    }
  }
  float dl[4], dv[4][6];
#pragma unroll
  for (int t = 0; t < 4; t++) {
    long bs = (long)(1 + t) * SO + base0;
    dl[t] = (float)O5[bs + lane];
    const unsigned* vp = (const unsigned*)(O5 + bs + 64 + lane * 6);
#pragma unroll
    for (int q = 0; q < 3; q++) {
      UU c; c.u = vp[q];
      dv[t][2 * q] = (float)c.h[0];
      dv[t][2 * q + 1] = (float)c.h[1];
    }
  }
  float mx = lg;
#pragma unroll
  for (int off = 32; off >= 1; off >>= 1) mx = fmaxf(mx, __shfl_xor(mx, off));
  float e = __expf(lg - mx);
  float S = e;
#pragma unroll
  for (int off = 32; off >= 1; off >>= 1) S += __shfl_xor(S, off);
  float pv = e / S;
  float st[4];
#pragma unroll
  for (int t = 0; t < 4; t++) {
    float v = pv * dl[t];
#pragma unroll
    for (int off = 32; off >= 1; off >>= 1) v += __shfl_xor(v, off);
    st[t] = v;
  }
  float da[4][6];
#pragma unroll
  for (int t = 0; t < 4; t++) {
    float w = pv * (dl[t] - st[t]);
#pragma unroll
    for (int k = 0; k < 6; k++) {
      float v = w * vals[k] + pv * dv[t][k];
#pragma unroll
      for (int off = 32; off >= 1; off >>= 1) v += __shfl_xor(v, off);
      da[t][k] = v;
    }
  }
  if (lane == 0) {
    // triu pairs (0,1)=0 (0,2)=1 (0,3)=2 (1,2)=3 (1,3)=4 (2,3)=5 ; u_i = sum_j dA_ij/dz_j
    float u0 = da[1][0] + da[2][1] + da[3][2];
    float u1 = -da[0][0] + da[2][3] + da[3][4];
    float u2 = -da[0][1] - da[1][3] + da[3][5];
    float u3 = -da[0][2] - da[1][4] - da[2][5];
    long ob = (long)(chunkBase + lb) * 4;
    if (*flag) {
      float* o = (float*)outp;
      o[ob] = 10.f * u0; o[ob + 1] = u1; o[ob + 2] = u2; o[ob + 3] = u3;
    } else {
      __hip_bfloat16* o = (__hip_bfloat16*)outp;
      o[ob] = __float2bfloat16(10.f * u0);
      o[ob + 1] = __float2bfloat16(u1);
      o[ob + 2] = __float2bfloat16(u2);
      o[ob + 3] = __float2bfloat16(u3);
    }
  }
}

extern "C" void kernel_launch(void* const* d_in, const int* in_sizes, int n_in,
                              void* d_out, int out_size, void* d_ws, size_t ws_size,
                              hipStream_t stream) {
  const void* x = d_in[0];
  const void* W0 = d_in[1];
  const void* b0 = d_in[2];
  const void* Wh = d_in[3];
  const void* bh = d_in[4];
  const void* Wout = d_in[5];
  const void* bout = d_in[6];
  const int B = in_sizes[0] / 4;  // 65536

  // workspace carve
  char* p = (char*)d_ws;
  int* flag = (int*)p;                 p += 256;
  _Float16* W0c = (_Float16*)p;        p += 4096 * 2;
  _Float16* x16 = (_Float16*)p;        p += (size_t)B * 4 * 2;
  _Float16* WhT = (_Float16*)p;        p += (size_t)4 * 1024 * 1024 * 2;
  _Float16* WoutT = (_Float16*)p;      p += (size_t)512 * 1024 * 2;  // padded 448->512 rows
  size_t used = (size_t)(p - (char*)d_ws);
  size_t rem = (ws_size > used) ? (ws_size - used) : 0;
  const size_t perS = 5 * 1024 * 2 * 2;  // H + PRE bytes per sample
  long bcap = (long)(rem / perS);
  int Bc = 128;
  while ((long)Bc * 2 <= bcap && Bc * 2 <= B) Bc *= 2;  // power of two, divides B
  _Float16* H = (_Float16*)p;          p += (size_t)5 * Bc * 1024 * 2;
  _Float16* PRE = (_Float16*)p;

  // dtype probe + weight prep (once per call)
  probe_kernel<<<1, 256, 0, stream>>>((const unsigned short*)W0, flag);
  cvt_kernel<<<(B * 4 + 255) / 256, 256, 0, stream>>>(x, x16, B * 4, flag);
  cvt_kernel<<<16, 256, 0, stream>>>(W0, W0c, 4096, flag);
  tr_kernel<<<dim3(32, 32, 4), dim3(32, 8), 0, stream>>>(Wh, WhT, 1024, 1024L * 1024, 1024L * 1024, flag);
  tr_kernel<<<dim3(32, 16, 1), dim3(32, 8), 0, stream>>>(Wout, WoutT, 448, 0L, 0L, flag);

  const int nChunks = B / Bc;
  for (int c = 0; c < nChunks; c++) {
    const int base = c * Bc;
    const int S1 = Bc * 1024;
    layer0_kernel<<<Bc, 256, 0, stream>>>(x16, W0c, (const __hip_bfloat16*)b0, H, base, S1);
    for (int l = 0; l < 4; l++) {
      gemm_f16<<<dim3(5 * Bc / 128, 8), 256, 0, stream>>>(
          H, WhT + (size_t)l * 1024 * 1024, ((const __hip_bfloat16*)bh) + l * 1024, PRE, 1024, 1024);
      act_kernel<<<(Bc * 128 + 255) / 256, 256, 0, stream>>>(PRE, H, S1, Bc * 128);
    }
    gemm_f16<<<dim3(5 * Bc / 128, 4), 256, 0, stream>>>(
        H, WoutT, (const __hip_bfloat16*)bout, PRE, 448, 448);
    finalize_kernel<<<Bc / 4, 256, 0, stream>>>(PRE, d_out, base, Bc, flag);
  }
}

// Round 2
// 4808.083 us; speedup vs baseline: 1.1297x; 1.1297x over previous
//
#include <hip/hip_runtime.h>
#include <hip/hip_bf16.h>

typedef _Float16 half8 __attribute__((ext_vector_type(8)));
typedef _Float16 half4 __attribute__((ext_vector_type(4)));
typedef float floatx4 __attribute__((ext_vector_type(4)));

__device__ __forceinline__ float bfu2f(unsigned short u) {
  return __uint_as_float(((unsigned)u) << 16);
}

__device__ __forceinline__ void gld16(const void* g, void* l) {
  __builtin_amdgcn_global_load_lds((const __attribute__((address_space(1))) void*)g,
                                   (__attribute__((address_space(3))) void*)l, 16, 0, 0);
}

__device__ __forceinline__ float fast_sig(float v) {
  return __builtin_amdgcn_rcpf(1.f + __expf(-v));
}

// ---------- probe: detect fp32 vs bf16 inputs (writes flag: 1 = fp32) ----------
__global__ void probe_kernel(const unsigned short* __restrict__ w0, int* __restrict__ flag) {
  __shared__ int s;
  if (threadIdx.x == 0) s = 0;
  __syncthreads();
  int big = 0;
  for (int i = threadIdx.x; i < 2048; i += 256) {
    unsigned e = (w0[i] >> 7) & 0xFFu;
    if (e >= 134u) big = 1;  // |val| >= 128 impossible for bf16 N(0,0.7) weights
  }
  if (big) atomicOr(&s, 1);
  __syncthreads();
  if (threadIdx.x == 0) *flag = s;
}

// ---------- generic convert to fp16 (zero-pads nIn..nOut) ----------
__global__ void cvt_kernel(const void* __restrict__ in, _Float16* __restrict__ out, int nOut,
                           int nIn, const int* __restrict__ flag) {
  int i = blockIdx.x * 256 + threadIdx.x;
  if (i >= nOut) return;
  float v = 0.f;
  if (i < nIn) v = (*flag) ? ((const float*)in)[i] : bfu2f(((const unsigned short*)in)[i]);
  out[i] = (_Float16)v;
}

// ---------- transpose+convert: out[z][n][k] = in[z][k][n] (n<Nin else 0), K=1024 ----------
__global__ void tr_kernel(const void* __restrict__ in, _Float16* __restrict__ out, int Nin,
                          long inStride, long outStride, const int* __restrict__ flag) {
  __shared__ float tile[32][33];
  const int f = *flag;
  int k0 = blockIdx.x * 32, n0 = blockIdx.y * 32;
  long ib = (long)blockIdx.z * inStride;
  long ob = (long)blockIdx.z * outStride;
  int tx = threadIdx.x, ty = threadIdx.y;  // 32 x 8
#pragma unroll
  for (int i = 0; i < 4; i++) {
    int k = k0 + ty + i * 8, n = n0 + tx;
    float v = 0.f;
    if (n < Nin) {
      long idx = ib + (long)k * Nin + n;
      v = f ? ((const float*)in)[idx] : bfu2f(((const unsigned short*)in)[idx]);
    }
    tile[ty + i * 8][tx] = v;
  }
  __syncthreads();
#pragma unroll
  for (int i = 0; i < 4; i++) {
    int n = n0 + ty + i * 8, k = k0 + tx;
    out[ob + (long)n * 1024 + k] = (_Float16)tile[tx][ty + i * 8];
  }
}

// ---------- layer 0: primal + 4 tangent init ----------
__global__ __launch_bounds__(256)
void layer0_kernel(const _Float16* __restrict__ x16, const _Float16* __restrict__ W0c,
                   const _Float16* __restrict__ b0c, _Float16* __restrict__ H,
                   int chunkBase, int S1) {
  const int lb = blockIdx.x;
  const int t = threadIdx.x;
  const long gb = (long)chunkBase + lb;
  float z0 = (float)x16[gb * 4 + 0];
  float z1 = (float)x16[gb * 4 + 1];
  float z2 = (float)x16[gb * 4 + 2];
  float z3 = (float)x16[gb * 4 + 3];
  const int j0 = t * 4;
  float w[4][4];
#pragma unroll
  for (int i = 0; i < 4; i++) {
    half4 wv = *(const half4*)&W0c[i * 1024 + j0];
#pragma unroll
    for (int jj = 0; jj < 4; jj++) w[i][jj] = (float)wv[jj];
  }
  half4 o[5];
#pragma unroll
  for (int jj = 0; jj < 4; jj++) {
    float pre = z0 * w[0][jj] + z1 * w[1][jj] + z2 * w[2][jj] + z3 * w[3][jj] +
                (float)b0c[j0 + jj];
    float s = fast_sig(pre);
    o[0][jj] = (_Float16)(pre * s);
    float ds = s * (1.f + pre * (1.f - s));
    o[1][jj] = (_Float16)(ds * w[0][jj]);
    o[2][jj] = (_Float16)(ds * w[1][jj]);
    o[3][jj] = (_Float16)(ds * w[2][jj]);
    o[4][jj] = (_Float16)(ds * w[3][jj]);
  }
  long rowbase = (long)lb * 1024 + j0;
#pragma unroll
  for (int s = 0; s < 5; s++) *(half4*)&H[(long)s * S1 + rowbase] = o[s];
}

// ---------- fp16 GEMM with fused epilogues ----------
// MODE 0: C = A*Bt^T (+bias for rows < biasRows)                [output layer]
// MODE 1: v = A*Bt^T + bias; C = silu(v); DS = silu'(v)         [hidden, stream 0]
// MODE 2: v = A*Bt^T; C = DS[row & bcMask][col] * v             [hidden, streams 1-4]
template <int MODE>
__global__ __launch_bounds__(256)
void gemm_f16(const _Float16* __restrict__ A, const _Float16* __restrict__ Bt,
              const _Float16* __restrict__ bias, _Float16* __restrict__ C,
              _Float16* __restrict__ DS, int Nreal, int ldc, int biasRows, int bcMask) {
  constexpr int K = 1024;
  __shared__ _Float16 As[128 * 32];
  __shared__ _Float16 Bs[128 * 32];
  const int tid = threadIdx.x;
  const int wave = tid >> 6;
  const int lane = tid & 63;
  const long m0 = (long)blockIdx.x * 128;
  const int n0 = blockIdx.y * 128;

  const int srow0 = (wave * 2 + 0) * 16 + (lane >> 2);
  const int srow1 = (wave * 2 + 1) * 16 + (lane >> 2);
  const int scol = (lane & 3) * 8;
  const _Float16* gA0 = A + (m0 + srow0) * K + scol;
  const _Float16* gA1 = A + (m0 + srow1) * K + scol;
  const _Float16* gB0 = Bt + (long)(n0 + srow0) * K + scol;
  const _Float16* gB1 = Bt + (long)(n0 + srow1) * K + scol;
  _Float16* lA0 = As + (wave * 2 + 0) * 512;  // wave-uniform LDS bases
  _Float16* lA1 = As + (wave * 2 + 1) * 512;
  _Float16* lB0 = Bs + (wave * 2 + 0) * 512;
  _Float16* lB1 = Bs + (wave * 2 + 1) * 512;

  const int wm = (wave & 1) * 64;
  const int wn = (wave >> 1) * 64;
  const int fr = lane & 15;
  const int fc = (lane >> 4) * 8;

  floatx4 acc[4][4];
#pragma unroll
  for (int i = 0; i < 4; i++)
#pragma unroll
    for (int j = 0; j < 4; j++) acc[i][j] = (floatx4)(0.f);

  for (int kk = 0; kk < K; kk += 32) {
    __syncthreads();
    gld16(gA0 + kk, lA0);
    gld16(gA1 + kk, lA1);
    gld16(gB0 + kk, lB0);
    gld16(gB1 + kk, lB1);
    __syncthreads();
    half8 af[4], bf[4];
#pragma unroll
    for (int i = 0; i < 4; i++) af[i] = *(const half8*)&As[(wm + i * 16 + fr) * 32 + fc];
#pragma unroll
    for (int i = 0; i < 4; i++) bf[i] = *(const half8*)&Bs[(wn + i * 16 + fr) * 32 + fc];
#pragma unroll
    for (int mi = 0; mi < 4; mi++)
#pragma unroll
      for (int ni = 0; ni < 4; ni++)
        acc[mi][ni] = __builtin_amdgcn_mfma_f32_16x16x32_f16(af[mi], bf[ni], acc[mi][ni], 0, 0, 0);
  }

  const int col0 = lane & 15;
  const int rq = (lane >> 4) * 4;
  float bv[4];
#pragma unroll
  for (int ni = 0; ni < 4; ni++) {
    int col = n0 + wn + ni * 16 + col0;
    bv[ni] = (MODE != 2 && col < Nreal) ? (float)bias[col] : 0.f;
  }
#pragma unroll
  for (int mi = 0; mi < 4; mi++) {
#pragma unroll
    for (int ni = 0; ni < 4; ni++) {
      int col = n0 + wn + ni * 16 + col0;
      if (col < Nreal) {
#pragma unroll
        for (int r = 0; r < 4; r++) {
          long row = m0 + wm + mi * 16 + rq + r;
          float v = acc[mi][ni][r];
          if (MODE == 0) {
            if (row < biasRows) v += bv[ni];
            C[row * (long)ldc + col] = (_Float16)v;
          } else if (MODE == 1) {
            v += bv[ni];
            float s = fast_sig(v);
            C[row * (long)ldc + col] = (_Float16)(v * s);
            DS[row * (long)1024 + col] = (_Float16)(s * (1.f + v * (1.f - s)));
          } else {
            float d = (float)DS[(long)(row & bcMask) * 1024 + col];
            C[row * (long)ldc + col] = (_Float16)(d * v);
          }
        }
      }
    }
  }
}

// ---------- finalize: softmax mixture + antisymmetric divergence; 1 wave = 1 sample ----------
__global__ __launch_bounds__(256)
void finalize_kernel(const _Float16* __restrict__ O5, void* __restrict__ outp,
                     int chunkBase, int Bc, const int* __restrict__ flag) {
  const int wid = threadIdx.x >> 6;
  const int lane = threadIdx.x & 63;  // lane == mixture index (N_MIX == 64)
  const int lb = blockIdx.x * 4 + wid;
  const long SO = (long)Bc * 448;
  const long base0 = (long)lb * 448;

  union UU { unsigned u; _Float16 h[2]; };

  float lg = (float)O5[base0 + lane];
  float vals[6];
  {
    const unsigned* vp = (const unsigned*)(O5 + base0 + 64 + lane * 6);
#pragma unroll
    for (int q = 0; q < 3; q++) {
      UU c; c.u = vp[q];
      vals[2 * q] = (float)c.h[0];
      vals[2 * q + 1] = (float)c.h[1];
    }
  }
  float dl[4], dv[4][6];
#pragma unroll
  for (int t = 0; t < 4; t++) {
    long bs = (long)(1 + t) * SO + base0;
    dl[t] = (float)O5[bs + lane];
    const unsigned* vp = (const unsigned*)(O5 + bs + 64 + lane * 6);
#pragma unroll
    for (int q = 0; q < 3; q++) {
      UU c; c.u = vp[q];
      dv[t][2 * q] = (float)c.h[0];
      dv[t][2 * q + 1] = (float)c.h[1];
    }
  }
  float mx = lg;
#pragma unroll
  for (int off = 32; off >= 1; off >>= 1) mx = fmaxf(mx, __shfl_xor(mx, off));
  float e = __expf(lg - mx);
  float S = e;
#pragma unroll
  for (int off = 32; off >= 1; off >>= 1) S += __shfl_xor(S, off);
  float pv = e / S;
  float st[4];
#pragma unroll
  for (int t = 0; t < 4; t++) {
    float v = pv * dl[t];
#pragma unroll
    for (int off = 32; off >= 1; off >>= 1) v += __shfl_xor(v, off);
    st[t] = v;
  }
  float da[4][6];
#pragma unroll
  for (int t = 0; t < 4; t++) {
    float w = pv * (dl[t] - st[t]);
#pragma unroll
    for (int k = 0; k < 6; k++) {
      float v = w * vals[k] + pv * dv[t][k];
#pragma unroll
      for (int off = 32; off >= 1; off >>= 1) v += __shfl_xor(v, off);
      da[t][k] = v;
    }
  }
  if (lane == 0) {
    // triu pairs (0,1)=0 (0,2)=1 (0,3)=2 (1,2)=3 (1,3)=4 (2,3)=5 ; u_i = sum_j dA_ij/dz_j
    float u0 = da[1][0] + da[2][1] + da[3][2];
    float u1 = -da[0][0] + da[2][3] + da[3][4];
    float u2 = -da[0][1] - da[1][3] + da[3][5];
    float u3 = -da[0][2] - da[1][4] - da[2][5];
    long ob = (long)(chunkBase + lb) * 4;
    if (*flag) {
      float* o = (float*)outp;
      o[ob] = 10.f * u0; o[ob + 1] = u1; o[ob + 2] = u2; o[ob + 3] = u3;
    } else {
      __hip_bfloat16* o = (__hip_bfloat16*)outp;
      o[ob] = __float2bfloat16(10.f * u0);
      o[ob + 1] = __float2bfloat16(u1);
      o[ob + 2] = __float2bfloat16(u2);
      o[ob + 3] = __float2bfloat16(u3);
    }
  }
}

extern "C" void kernel_launch(void* const* d_in, const int* in_sizes, int n_in,
                              void* d_out, int out_size, void* d_ws, size_t ws_size,
                              hipStream_t stream) {
  const void* x = d_in[0];
  const void* W0 = d_in[1];
  const void* b0 = d_in[2];
  const void* Wh = d_in[3];
  const void* bh = d_in[4];
  const void* Wout = d_in[5];
  const void* bout = d_in[6];
  const int B = in_sizes[0] / 4;  // 65536

  // workspace carve (all 256B-aligned)
  char* p = (char*)d_ws;
  int* flag = (int*)p;                 p += 256;
  _Float16* W0c = (_Float16*)p;        p += 4096 * 2;
  _Float16* b0c = (_Float16*)p;        p += 1024 * 2;
  _Float16* bhc = (_Float16*)p;        p += 4096 * 2;
  _Float16* boutc = (_Float16*)p;      p += 512 * 2;
  p += 256 - ((size_t)(p - (char*)d_ws) & 255);
  _Float16* x16 = (_Float16*)p;        p += (size_t)B * 4 * 2;
  _Float16* WhT = (_Float16*)p;        p += (size_t)4 * 1024 * 1024 * 2;
  _Float16* WoutT = (_Float16*)p;      p += (size_t)512 * 1024 * 2;  // padded 448->512 rows
  size_t used = (size_t)(p - (char*)d_ws);
  size_t rem = (ws_size > used) ? (ws_size - used) : 0;
  // per-sample: Ha(10240) + Hb(10240) + DS(2048) + PREo(4480)
  const size_t perS = 10240 + 10240 + 2048 + 4480;
  long bcap = (long)(rem / perS);
  int Bc = 128;
  while ((long)Bc * 2 <= bcap && Bc * 2 <= B) Bc *= 2;  // power of two, divides B
  _Float16* Ha = (_Float16*)p;         p += (size_t)5 * Bc * 1024 * 2;
  _Float16* Hb = (_Float16*)p;         p += (size_t)5 * Bc * 1024 * 2;
  _Float16* DS = (_Float16*)p;         p += (size_t)Bc * 1024 * 2;
  _Float16* PREo = (_Float16*)p;

  // dtype probe + weight prep (once per call)
  probe_kernel<<<1, 256, 0, stream>>>((const unsigned short*)W0, flag);
  cvt_kernel<<<(B * 4 + 255) / 256, 256, 0, stream>>>(x, x16, B * 4, B * 4, flag);
  cvt_kernel<<<16, 256, 0, stream>>>(W0, W0c, 4096, 4096, flag);
  cvt_kernel<<<4, 256, 0, stream>>>(b0, b0c, 1024, 1024, flag);
  cvt_kernel<<<16, 256, 0, stream>>>(bh, bhc, 4096, 4096, flag);
  cvt_kernel<<<2, 256, 0, stream>>>(bout, boutc, 512, 448, flag);
  tr_kernel<<<dim3(32, 32, 4), dim3(32, 8), 0, stream>>>(Wh, WhT, 1024, 1024L * 1024, 1024L * 1024, flag);
  tr_kernel<<<dim3(32, 16, 1), dim3(32, 8), 0, stream>>>(Wout, WoutT, 448, 0L, 0L, flag);

  const int nChunks = B / Bc;
  for (int c = 0; c < nChunks; c++) {
    const int base = c * Bc;
    const int S1 = Bc * 1024;
    _Float16* Hin = Ha;
    _Float16* Hout = Hb;
    layer0_kernel<<<Bc, 256, 0, stream>>>(x16, W0c, b0c, Hin, base, S1);
    for (int l = 0; l < 4; l++) {
      const _Float16* Wl = WhT + (size_t)l * 1024 * 1024;
      const _Float16* bl = bhc + l * 1024;
      // stream 0: silu + DS
      gemm_f16<1><<<dim3(Bc / 128, 8), 256, 0, stream>>>(
          Hin, Wl, bl, Hout, DS, 1024, 1024, Bc, 0);
      // streams 1-4: scale by DS
      gemm_f16<2><<<dim3(4 * Bc / 128, 8), 256, 0, stream>>>(
          Hin + S1, Wl, nullptr, Hout + S1, DS, 1024, 1024, 0, Bc - 1);
      _Float16* t = Hin; Hin = Hout; Hout = t;
    }
    gemm_f16<0><<<dim3(5 * Bc / 128, 4), 256, 0, stream>>>(
        Hin, WoutT, boutc, PREo, nullptr, 448, 448, Bc, 0);
    finalize_kernel<<<Bc / 4, 256, 0, stream>>>(PREo, d_out, base, Bc, flag);
  }
}